// Round 1
// baseline (3153.868 us; speedup 1.0000x reference)
//
#include <hip/hip_runtime.h>
#include <hip/hip_bf16.h>
#include <math.h>

typedef __bf16 bf16;
typedef __bf16 bf16x4 __attribute__((ext_vector_type(4)));
typedef __bf16 bf16x8 __attribute__((ext_vector_type(8)));
typedef float f32x4 __attribute__((ext_vector_type(4)));

#define B_ 4
#define T_ 8192
#define D_ 512
#define H_ 16
#define HD_ 32
#define M_ (B_ * T_)  // 32768 rows

// ---------------- fp32 -> bf16 convert (vectorized, grid-stride) ----------------
__global__ void k_cvt(const float* __restrict__ in, bf16* __restrict__ out, int n4) {
  int i = blockIdx.x * blockDim.x + threadIdx.x;
  const int stride = gridDim.x * blockDim.x;
  for (; i < n4; i += stride) {
    const float4 v = ((const float4*)in)[i];
    bf16x4 o;
    o.x = (bf16)v.x; o.y = (bf16)v.y; o.z = (bf16)v.z; o.w = (bf16)v.w;
    ((bf16x4*)out)[i] = o;
  }
}

// ---------------- 512x512 transpose + convert (W -> W^T bf16) ----------------
// wT[n][k] = W[k][n]. Writes coalesced; strided reads are L2-cached (1 MB).
__global__ void k_cvt_T(const float* __restrict__ w, bf16* __restrict__ wT) {
  const int tid = blockIdx.x * blockDim.x + threadIdx.x;  // 0..262143
  const int n = tid >> 9, k = tid & 511;
  wT[tid] = (bf16)w[k * 512 + n];
}

// ---------------- bf16 GEMM: C[M x 512] = A[M x 512] * B, B given as BT[512 x 512] ----------------
// 128x128 tile, BK=32, 4 waves each computing 64x64 via 4x4 mfma_f32_16x16x32_bf16.
// LDS rows padded to 40 elems (80 B = 5*16 B, odd 16B-stride => conflict-free b128 frag reads).
template <int OUTF32>
__global__ __launch_bounds__(256) void k_gemm(const bf16* __restrict__ A,
                                              const bf16* __restrict__ BT,
                                              void* __restrict__ Cout,
                                              const float* __restrict__ bias) {
  __shared__ bf16 As[128][40];
  __shared__ bf16 Bs[128][40];
  const int bn = blockIdx.x * 128;
  const int bm = blockIdx.y * 128;
  const int tid = threadIdx.x;
  const int l = tid & 63, wid = tid >> 6;
  const int ln = l & 15, ku = l >> 4;                 // fragment lane decomposition
  const int wm = (wid >> 1) * 64, wn = (wid & 1) * 64;  // wave's 64x64 sub-tile
  const int sr = tid >> 2, sc = (tid & 3) * 8;        // staging: row, col-chunk

  f32x4 acc[4][4] = {};

  for (int ks = 0; ks < 512; ks += 32) {
    __syncthreads();
    *(bf16x8*)&As[sr][sc]      = *(const bf16x8*)&A[(size_t)(bm + sr) * 512 + ks + sc];
    *(bf16x8*)&As[sr + 64][sc] = *(const bf16x8*)&A[(size_t)(bm + sr + 64) * 512 + ks + sc];
    *(bf16x8*)&Bs[sr][sc]      = *(const bf16x8*)&BT[(size_t)(bn + sr) * 512 + ks + sc];
    *(bf16x8*)&Bs[sr + 64][sc] = *(const bf16x8*)&BT[(size_t)(bn + sr + 64) * 512 + ks + sc];
    __syncthreads();

    bf16x8 af[4], bfr[4];
#pragma unroll
    for (int mt = 0; mt < 4; ++mt) af[mt] = *(const bf16x8*)&As[wm + mt * 16 + ln][ku * 8];
#pragma unroll
    for (int nt = 0; nt < 4; ++nt) bfr[nt] = *(const bf16x8*)&Bs[wn + nt * 16 + ln][ku * 8];
#pragma unroll
    for (int mt = 0; mt < 4; ++mt)
#pragma unroll
      for (int nt = 0; nt < 4; ++nt)
        acc[mt][nt] = __builtin_amdgcn_mfma_f32_16x16x32_bf16(af[mt], bfr[nt], acc[mt][nt], 0, 0, 0);
  }

  // epilogue: C/D layout col = lane&15, row = (lane>>4)*4 + reg
#pragma unroll
  for (int mt = 0; mt < 4; ++mt)
#pragma unroll
    for (int nt = 0; nt < 4; ++nt)
#pragma unroll
      for (int r = 0; r < 4; ++r) {
        const int row = bm + wm + mt * 16 + ku * 4 + r;
        const int col = bn + wn + nt * 16 + ln;
        const float v = acc[mt][nt][r];
        if (OUTF32)
          ((float*)Cout)[(size_t)row * 512 + col] = v + bias[col];
        else
          ((bf16*)Cout)[(size_t)row * 512 + col] = (bf16)v;
      }
}

// ---------------- flash attention, bf16 MFMA, online softmax ----------------
// grid (qt=128, bh=64), 256 threads = 4 waves. Wave w owns 16 q-rows.
// Per kv-block of 64: QK^T = 4 MFMAs, softmax update, P via per-wave LDS, PV = 4 MFMAs.
__global__ __launch_bounds__(256) void k_attn(const bf16* __restrict__ Q,
                                              const bf16* __restrict__ K,
                                              const bf16* __restrict__ V,
                                              bf16* __restrict__ O) {
  __shared__ bf16 vt[32][72];       // V^T tile: [d][kv], 144 B rows (odd 16B stride)
  __shared__ bf16 pl[4][16][72];    // per-wave P: [q][kv]
  const int qt = blockIdx.x;        // q-tile (64 rows)
  const int bh = blockIdx.y;
  const int b = bh >> 4, h = bh & 15;
  const size_t base = (size_t)b * T_ * 512 + (size_t)h * 32;
  const int tid = threadIdx.x;
  const int l = tid & 63, w = tid >> 6;
  const int ln = l & 15, ku = l >> 4;

  // Q A-fragment: row = ln (within wave's 16 rows), k = ku*8..+8
  const int qrow = qt * 64 + w * 16 + ln;
  const bf16x8 qa = *(const bf16x8*)&Q[base + (size_t)qrow * 512 + ku * 8];

  float m[4], Z[4];
  f32x4 o0 = {}, o1 = {};
#pragma unroll
  for (int r = 0; r < 4; ++r) { m[r] = -INFINITY; Z[r] = 0.0f; }

  const int vr = tid >> 2, vc = (tid & 3) * 8;  // V staging decomposition
  const float scale = 0.17677669529663687f;     // 1/sqrt(32)

  for (int kb = 0; kb < 128; ++kb) {
    const int kv0 = kb * 64;
    __syncthreads();
    // stage V^T: each thread loads 8 contiguous bf16 of V row (kv0+vr), scatters to vt[d][kv]
    {
      const bf16x8 vv = *(const bf16x8*)&V[base + (size_t)(kv0 + vr) * 512 + vc];
#pragma unroll
      for (int i = 0; i < 8; ++i) vt[vc + i][vr] = vv[i];
    }
    __syncthreads();

    // QK^T: B-fragment of K^T read directly from global (L2-resident)
    f32x4 s[4];
#pragma unroll
    for (int t = 0; t < 4; ++t) {
      const bf16x8 kf = *(const bf16x8*)&K[base + (size_t)(kv0 + t * 16 + ln) * 512 + ku * 8];
      const f32x4 z = {};
      s[t] = __builtin_amdgcn_mfma_f32_16x16x32_bf16(qa, kf, z, 0, 0, 0);
    }

    // online softmax per q-row r (row = ku*4+r in C layout; 16 lanes per row group)
#pragma unroll
    for (int r = 0; r < 4; ++r) {
      float sv0 = s[0][r] * scale, sv1 = s[1][r] * scale;
      float sv2 = s[2][r] * scale, sv3 = s[3][r] * scale;
      float mx = fmaxf(fmaxf(sv0, sv1), fmaxf(sv2, sv3));
      mx = fmaxf(mx, __shfl_xor(mx, 1));
      mx = fmaxf(mx, __shfl_xor(mx, 2));
      mx = fmaxf(mx, __shfl_xor(mx, 4));
      mx = fmaxf(mx, __shfl_xor(mx, 8));
      const float mn = fmaxf(m[r], mx);
      const float alpha = __expf(m[r] - mn);
      const float p0 = __expf(sv0 - mn);
      const float p1 = __expf(sv1 - mn);
      const float p2 = __expf(sv2 - mn);
      const float p3 = __expf(sv3 - mn);
      pl[w][ku * 4 + r][0 * 16 + ln] = (bf16)p0;
      pl[w][ku * 4 + r][1 * 16 + ln] = (bf16)p1;
      pl[w][ku * 4 + r][2 * 16 + ln] = (bf16)p2;
      pl[w][ku * 4 + r][3 * 16 + ln] = (bf16)p3;
      float ps = p0 + p1 + p2 + p3;
      ps += __shfl_xor(ps, 1);
      ps += __shfl_xor(ps, 2);
      ps += __shfl_xor(ps, 4);
      ps += __shfl_xor(ps, 8);
      Z[r] = Z[r] * alpha + ps;
      m[r] = mn;
      o0[r] *= alpha;
      o1[r] *= alpha;
    }

    // PV: A-frags from per-wave P (within-wave LDS RAW handled by lgkmcnt), B-frags from vt
    const bf16x8 pa0 = *(const bf16x8*)&pl[w][ln][ku * 8];
    const bf16x8 pa1 = *(const bf16x8*)&pl[w][ln][32 + ku * 8];
    const bf16x8 vb00 = *(const bf16x8*)&vt[ln][ku * 8];
    const bf16x8 vb01 = *(const bf16x8*)&vt[ln][32 + ku * 8];
    const bf16x8 vb10 = *(const bf16x8*)&vt[16 + ln][ku * 8];
    const bf16x8 vb11 = *(const bf16x8*)&vt[16 + ln][32 + ku * 8];
    o0 = __builtin_amdgcn_mfma_f32_16x16x32_bf16(pa0, vb00, o0, 0, 0, 0);
    o0 = __builtin_amdgcn_mfma_f32_16x16x32_bf16(pa1, vb01, o0, 0, 0, 0);
    o1 = __builtin_amdgcn_mfma_f32_16x16x32_bf16(pa0, vb10, o1, 0, 0, 0);
    o1 = __builtin_amdgcn_mfma_f32_16x16x32_bf16(pa1, vb11, o1, 0, 0, 0);
  }

  // epilogue: O/(Z+1e-9), rows = ku*4+r (C layout), cols = dt*16+ln
#pragma unroll
  for (int r = 0; r < 4; ++r) {
    const float invz = 1.0f / (Z[r] + 1e-9f);
    const int orow = qt * 64 + w * 16 + ku * 4 + r;
    O[base + (size_t)orow * 512 + ln] = (bf16)(o0[r] * invz);
    O[base + (size_t)orow * 512 + 16 + ln] = (bf16)(o1[r] * invz);
  }
}

extern "C" void kernel_launch(void* const* d_in, const int* in_sizes, int n_in,
                              void* d_out, int out_size, void* d_ws, size_t ws_size,
                              hipStream_t stream) {
  const float* x = (const float*)d_in[0];
  const float* Wq = (const float*)d_in[1];
  const float* Wk = (const float*)d_in[2];
  const float* Wv = (const float*)d_in[3];
  const float* Wo = (const float*)d_in[4];
  const float* bo = (const float*)d_in[5];
  float* out = (float*)d_out;

  char* ws = (char*)d_ws;
  const size_t SZ = (size_t)M_ * 512 * sizeof(bf16);  // 32 MiB per activation buffer
  bf16* xb = (bf16*)(ws);
  bf16* qb = (bf16*)(ws + SZ);
  bf16* kb = (bf16*)(ws + 2 * SZ);
  bf16* vb = (bf16*)(ws + 3 * SZ);
  bf16* ob = (bf16*)(ws + 4 * SZ);
  bf16* wqT = (bf16*)(ws + 5 * SZ);
  bf16* wkT = wqT + 512 * 512;
  bf16* wvT = wkT + 512 * 512;
  bf16* woT = wvT + 512 * 512;

  // 1) converts
  k_cvt<<<2048, 256, 0, stream>>>(x, xb, M_ * 512 / 4);
  k_cvt_T<<<1024, 256, 0, stream>>>(Wq, wqT);
  k_cvt_T<<<1024, 256, 0, stream>>>(Wk, wkT);
  k_cvt_T<<<1024, 256, 0, stream>>>(Wv, wvT);
  k_cvt_T<<<1024, 256, 0, stream>>>(Wo, woT);

  // 2) QKV projections (bf16 out)
  dim3 gg(4, 256);
  k_gemm<0><<<gg, 256, 0, stream>>>(xb, wqT, qb, nullptr);
  k_gemm<0><<<gg, 256, 0, stream>>>(xb, wkT, kb, nullptr);
  k_gemm<0><<<gg, 256, 0, stream>>>(xb, wvT, vb, nullptr);

  // 3) flash attention
  dim3 ga(128, 64);
  k_attn<<<ga, 256, 0, stream>>>(qb, kb, vb, ob);

  // 4) output projection (f32 out + bias)
  k_gemm<1><<<gg, 256, 0, stream>>>(ob, woT, out, bo);
}